// Round 3
// baseline (74.699 us; speedup 1.0000x reference)
//
#include <hip/hip_runtime.h>

// Signature-kernel MMD, fused. R15 = R14 (71.83us verified) + ONE delta:
// 3-deep LDS prefetch pipeline in the PDE loop. R14's consume distance was
// 1 iteration (~60-100 cyc) vs ~120 cyc LDS latency -> structural stall
// every iteration. Now three rotating fp16 pair-buffers give distance 3
// (~200-300 cyc). #pragma unroll 3 matches the period-3 rotation so all
// buffer rotations become register renames (63 = 21*3, no remainder).
// Loads reach oA[132], inside the 212-elem rear pad (zeros, never consumed).

constexpr int S2  = 66;     // binc row stride (fp16 elems)
constexpr int PAD = 64;     // front pad (covers negative column offsets)
constexpr int BNA = 4368;   // per-pair buffer (PAD + 63*66 + rear pad, 16B-mult)

__device__ __forceinline__ float dpp_shr1(float v) {
    // result[l] = src[l-1], result[0] = 0
    return __builtin_bit_cast(float,
        __builtin_amdgcn_update_dpp(0, __builtin_bit_cast(int, v), 0x138, 0xF, 0xF, true));
}
__device__ __forceinline__ float dpp_shl1(float v) {
    // result[l] = src[l+1], result[63] = 0
    return __builtin_bit_cast(float,
        __builtin_amdgcn_update_dpp(0, __builtin_bit_cast(int, v), 0x130, 0xF, 0xF, true));
}
__device__ __forceinline__ float dot4(float4 a, float4 b) {
    return a.x * b.x + a.y * b.y + a.z * b.z + a.w * b.w;
}

// Two PDE substeps (antidiagonals 2k-1, 2k); ef/of are binc-MINUS-ONE values
// (the -1 is pre-folded at f32 conversion). Per substep: dpp + 2x(add+fma).
// State: p1E,p1O (diag d-1), p2E (E diag d-2), up2 (shr1 of O diag d-2),
// oP (previous body's of). Structure verified R3/R6; -1 fold verified R14.
#define BODY(ef, of) {                                 \
    float up1 = dpp_shr1(p1O);                         \
    float cE  = (up1 + p1E) + up2 * (ef);              \
    float cO  = (p1E + p1O) + p2E * oP;                \
    float nu2 = up1, np2 = p1E;                        \
    p1E = cE; p1O = cO;                                \
    up1 = dpp_shr1(p1O);                               \
    cE  = (up1 + p1E) + nu2 * (ef);                    \
    cO  = (p1E + p1O) + np2 * (of);                    \
    up2 = up1; p2E = p1E; p1E = cE; p1O = cO;          \
    oP  = (of); }

// Body with E derived from previous body's O float via DPP (verified R7/R8).
#define EBODY(foCur) {                                 \
    float eF = dpp_shr1(foPrev);                       \
    BODY(eF, foCur)                                    \
    foPrev = (foCur); }

__global__ __launch_bounds__(256) void sigpde_kernel(const float* __restrict__ x,
                                                     const float* __restrict__ y,
                                                     float* __restrict__ pws) {
    __shared__ __align__(16) _Float16 binc[4][BNA];   // 34944 B
    __shared__ float4 xs[4][64];                      //  4096 B
    __shared__ float  xxs[4][64];                     //  1024 B

    const int lane = threadIdx.x & 63;
    const int wid  = threadIdx.x >> 6;
    const int p = blockIdx.x * 4 + wid;     // 0..3071
    const int g = p >> 10;                  // 0: xx, 1: xy, 2: yy
    const int q = p & 1023;
    const int a = q >> 5, b = q & 31;
    const float* Ab = (g == 2) ? y : x;
    const float* Bb = (g == 0) ? x : y;

    _Float16* bw = &binc[wid][0];

    float4 xa = ((const float4*)(Ab + a * 256))[lane];
    float4 yv = ((const float4*)(Bb + b * 256))[lane];
    xs[wid][lane]  = xa;
    xxs[wid][lane] = dot4(xa, xa);
    const float yy = dot4(yv, yv);

    {   // zero this wave's buffer (pads/gaps must be finite zeros)
        uint4* z = (uint4*)bw;
        const uint4 zz = {0u, 0u, 0u, 0u};
        for (int i = lane; i < BNA / 8; i += 64) z[i] = zz;
    }
    // No barrier anywhere: all LDS is wave-private; same-wave ds ordering
    // is guaranteed via lgkmcnt.

    // De-phase the 3 co-resident blocks per CU (one-time, <=1280 cyc):
    // phase-locked waves stall in unison and TLP can't fill the bubbles.
    {
        const int ph = blockIdx.x % 3;
        if (ph == 1)      __builtin_amdgcn_s_sleep(10);  // ~640 cyc
        else if (ph == 2) __builtin_amdgcn_s_sleep(20);  // ~1280 cyc
    }

    // Gram + double increments (column = lane), verified R6:
    // binc[u-1][lane] = 0.25*((G[u][l+1]-G[u][l]) - (G[u-1][l+1]-G[u-1][l]))
    float dp = 0.0f;
    #pragma unroll 4
    for (int u = 0; u < 64; ++u) {
        float4 xu = xs[wid][u];            // broadcast read
        float t = xxs[wid][u] + yy - 2.0f * dot4(xu, yv);
        float gv = __expf(-0.5f * t);
        float d = dpp_shl1(gv) - gv;
        if (u > 0) bw[PAD + (u - 1) * S2 + lane] = (_Float16)(0.25f * (d - dp));
        dp = d;
    }

    // Goursat PDE: lane owns rows iE=2l, iO=2l+1; body k = diagonals 2k-1,2k.
    // Single O-stream: body k loads oA[k-1] = binc[l][k-1-l]; the E factor is
    // eF(k) = shr1(oF(k-1)) (lane l-1's O value of the previous body).
    const int rO = (lane <= 62) ? lane : 62;
    const _Float16* oA = bw + PAD + rO * S2 - lane;

    float p1E = (lane == 0) ? 1.0f : 0.0f;  // diag 0 seed: K[0,0]=1
    float p1O = 0.0f, p2E = 0.0f, up2 = 0.0f;
    float oP = -1.0f;                       // (0 - 1): -1-fold convention
    float foPrev = -1.0f;                   // oF(0): out-of-window 0 -> -1

    // warmup: bodies 1,2 converted; 3 pair-buffers in flight (3-deep pipe):
    // hA = bodies 3,4; hB = bodies 5,6; hC = bodies 7,8.
    float fo0 = (float)oA[0] - 1.0f, fo1 = (float)oA[1] - 1.0f;
    _Float16 hA0 = oA[2], hA1 = oA[3];
    _Float16 hB0 = oA[4], hB1 = oA[5];
    _Float16 hC0 = oA[6], hC1 = oA[7];

    #pragma unroll 3
    for (int k = 1; k <= 125; k += 2) {
        // convert the OLDEST buffer: bodies k+2,k+3 (loaded 3 iters ago)
        float gA0 = (float)hA0 - 1.0f, gA1 = (float)hA1 - 1.0f;
        // rotate buffers and issue the new loads: bodies k+8,k+9
        hA0 = hB0; hA1 = hB1;
        hB0 = hC0; hB1 = hC1;
        hC0 = oA[k + 7]; hC1 = oA[k + 8];
        // compute bodies k, k+1
        EBODY(fo0)
        EBODY(fo1)
        // feed next iteration's bodies
        fo0 = gA0; fo1 = gA1;
    }

    // K[126,126] = lane 63's E slot after diagonal 252. Plain store, no atomic.
    if (lane == 63) {
        float w = (g == 1) ? (-2.0f / 1024.0f) : (1.0f / 1024.0f);
        pws[p] = w * p1E;
    }
}

__global__ __launch_bounds__(256) void reduce_kernel(const float* __restrict__ pws,
                                                     float* __restrict__ out) {
    // Sum 3072 weighted partials (768 float4 loads), write out[0].
    float s = 0.0f;
    const float4* v = (const float4*)pws;
    for (int i = threadIdx.x; i < 768; i += 256) {
        float4 t = v[i];
        s += (t.x + t.y) + (t.z + t.w);
    }
    for (int off = 32; off > 0; off >>= 1) s += __shfl_down(s, off);
    __shared__ float ws[4];
    if ((threadIdx.x & 63) == 0) ws[threadIdx.x >> 6] = s;
    __syncthreads();
    if (threadIdx.x == 0) out[0] = (ws[0] + ws[1]) + (ws[2] + ws[3]);
}

extern "C" void kernel_launch(void* const* d_in, const int* in_sizes, int n_in,
                              void* d_out, int out_size, void* d_ws, size_t ws_size,
                              hipStream_t stream) {
    const float* x = (const float*)d_in[0];
    const float* y = (const float*)d_in[1];
    float* out = (float*)d_out;
    float* pws = (float*)d_ws;    // 3072 floats = 12 KB << ws_size
    (void)in_sizes; (void)n_in; (void)out_size; (void)ws_size;

    hipLaunchKernelGGL(sigpde_kernel, dim3(768), dim3(256), 0, stream, x, y, pws);
    hipLaunchKernelGGL(reduce_kernel, dim3(1), dim3(256), 0, stream, pws, out);
}

// Round 4
// 71.220 us; speedup vs baseline: 1.0489x; 1.0489x over previous
//
#include <hip/hip_runtime.h>

// Signature-kernel MMD, fused. R16 = R14 (71.83us verified; R15's 3-deep
// prefetch REVERTED - it regressed +2.9us) + pure instruction-count trims.
// Model: loop is issue-bound (~7ns per instr removed, R14/R15 both fit);
// latency-depth changes are neutral-to-negative. Trims:
//  (1) exp fold: xxs stores xx*C (C=-0.5*log2e), cyy=yy*C lane-const;
//      gv = exp2(fma(dot, log2e, cxx+cyy)) - removes add+mul per u (-128).
//  (2) 0.25 fold: store raw (d-dp) fp16 (x0.25 is exact pow2 - bitwise
//      identical rounding); PDE converts with fma(h,0.25,-1) (-63).
//  (3) peel u=0 from Gram loop -> unconditional store, 63 iters unroll 3.
//  (4) fully unrolled zero loop (8 stores + 1 predicated tail).

constexpr int S2  = 66;     // binc row stride (fp16 elems)
constexpr int PAD = 64;     // front pad (covers negative column offsets)
constexpr int BNA = 4368;   // per-pair buffer (PAD + 63*66 + rear pad, 16B-mult)

__device__ __forceinline__ float dpp_shr1(float v) {
    // result[l] = src[l-1], result[0] = 0   (wave_shr:1)
    return __builtin_bit_cast(float,
        __builtin_amdgcn_update_dpp(0, __builtin_bit_cast(int, v), 0x138, 0xF, 0xF, true));
}
__device__ __forceinline__ float dpp_shl1(float v) {
    // result[l] = src[l+1], result[63] = 0  (wave_shl:1)
    return __builtin_bit_cast(float,
        __builtin_amdgcn_update_dpp(0, __builtin_bit_cast(int, v), 0x130, 0xF, 0xF, true));
}
__device__ __forceinline__ float dot4(float4 a, float4 b) {
    return a.x * b.x + a.y * b.y + a.z * b.z + a.w * b.w;
}

// Two PDE substeps (antidiagonals 2k-1, 2k); ef/of are 0.25*binc-MINUS-ONE
// values (folded at f32 conversion). Per substep: dpp + 2x(add+fma).
// State: p1E,p1O (diag d-1), p2E (E diag d-2), up2 (shr1 of O diag d-2),
// oP (previous body's of). Structure verified R3/R6; -1 fold verified R14.
#define BODY(ef, of) {                                 \
    float up1 = dpp_shr1(p1O);                         \
    float cE  = (up1 + p1E) + up2 * (ef);              \
    float cO  = (p1E + p1O) + p2E * oP;                \
    float nu2 = up1, np2 = p1E;                        \
    p1E = cE; p1O = cO;                                \
    up1 = dpp_shr1(p1O);                               \
    cE  = (up1 + p1E) + nu2 * (ef);                    \
    cO  = (p1E + p1O) + np2 * (of);                    \
    up2 = up1; p2E = p1E; p1E = cE; p1O = cO;          \
    oP  = (of); }

// Body with E derived from previous body's O float via DPP (verified R7/R8).
#define EBODY(foCur) {                                 \
    float eF = dpp_shr1(foPrev);                       \
    BODY(eF, foCur)                                    \
    foPrev = (foCur); }

__global__ __launch_bounds__(256) void sigpde_kernel(const float* __restrict__ x,
                                                     const float* __restrict__ y,
                                                     float* __restrict__ pws) {
    __shared__ __align__(16) _Float16 binc[4][BNA];   // 34944 B
    __shared__ float4 xs[4][64];                      //  4096 B
    __shared__ float  xxs[4][64];                     //  1024 B

    const int lane = threadIdx.x & 63;
    const int wid  = threadIdx.x >> 6;
    const int p = blockIdx.x * 4 + wid;     // 0..3071
    const int g = p >> 10;                  // 0: xx, 1: xy, 2: yy
    const int q = p & 1023;
    const int a = q >> 5, b = q & 31;
    const float* Ab = (g == 2) ? y : x;
    const float* Bb = (g == 0) ? x : y;

    _Float16* bw = &binc[wid][0];

    const float C   = -0.72134752044448170f;  // -0.5*log2(e)
    const float L2E =  1.44269504088896340f;  // log2(e) = -2*C

    float4 xa = ((const float4*)(Ab + a * 256))[lane];
    float4 yv = ((const float4*)(Bb + b * 256))[lane];
    xs[wid][lane]  = xa;
    xxs[wid][lane] = C * dot4(xa, xa);        // pre-scaled by C
    const float cyy = C * dot4(yv, yv);       // lane-constant, pre-scaled

    {   // zero this wave's buffer (pads/gaps must be finite zeros)
        uint4* z = (uint4*)bw;
        const uint4 zz = {0u, 0u, 0u, 0u};
        #pragma unroll
        for (int j = 0; j < 8; ++j) z[lane + 64 * j] = zz;  // 512 of 546
        if (lane < 34) z[512 + lane] = zz;                   // tail
    }
    // No barrier anywhere: all LDS is wave-private; same-wave ds ordering
    // is guaranteed via lgkmcnt.

    // De-phase the 3 co-resident blocks per CU (one-time, <=1280 cyc).
    {
        const int ph = blockIdx.x % 3;
        if (ph == 1)      __builtin_amdgcn_s_sleep(10);  // ~640 cyc
        else if (ph == 2) __builtin_amdgcn_s_sleep(20);  // ~1280 cyc
    }

    // Gram + double increments (column = lane), verified R6:
    // gv = exp(-0.5*(xx+yy-2xy)) = exp2(fma(xy, log2e, cxx+cyy)).
    // binc[u-1][lane] stores RAW (d - dp); the 0.25 is folded in the PDE.
    float dp;
    {   // peeled u = 0
        float4 x0 = xs[wid][0];
        float g0 = __builtin_amdgcn_exp2f(
            __builtin_fmaf(dot4(x0, yv), L2E, xxs[wid][0] + cyy));
        dp = dpp_shl1(g0) - g0;
    }
    #pragma unroll 3
    for (int u = 1; u < 64; ++u) {
        float4 xu = xs[wid][u];            // broadcast read
        float gv = __builtin_amdgcn_exp2f(
            __builtin_fmaf(dot4(xu, yv), L2E, xxs[wid][u] + cyy));
        float d = dpp_shl1(gv) - gv;
        bw[PAD + (u - 1) * S2 + lane] = (_Float16)(d - dp);
        dp = d;
    }

    // Goursat PDE: lane owns rows iE=2l, iO=2l+1; body k = diagonals 2k-1,2k.
    // Single O-stream: body k loads oA[k-1] = binc[l][k-1-l]; the E factor is
    // eF(k) = shr1(oF(k-1)) (lane l-1's O value of the previous body).
    const int rO = (lane <= 62) ? lane : 62;
    const _Float16* oA = bw + PAD + rO * S2 - lane;

    float p1E = (lane == 0) ? 1.0f : 0.0f;  // diag 0 seed: K[0,0]=1
    float p1O = 0.0f, p2E = 0.0f, up2 = 0.0f;
    float oP = -1.0f;                       // (0*0.25 - 1): fold convention
    float foPrev = -1.0f;                   // oF(0): out-of-window 0 -> -1

    // warmup: bodies 1,2 converted; bodies 3,4 in flight (R14 structure)
    _Float16 ho2 = oA[2], ho3 = oA[3];
    float fo0 = __builtin_fmaf((float)oA[0], 0.25f, -1.0f);
    float fo1 = __builtin_fmaf((float)oA[1], 0.25f, -1.0f);

    #pragma unroll 2
    for (int k = 1; k <= 125; k += 2) {
        // convert bodies k+2, k+3 (loaded last iteration), fold 0.25 and -1
        float go2 = __builtin_fmaf((float)ho2, 0.25f, -1.0f);
        float go3 = __builtin_fmaf((float)ho3, 0.25f, -1.0f);
        // prefetch bodies k+4, k+5
        ho2 = oA[k + 3]; ho3 = oA[k + 4];
        // compute bodies k, k+1
        EBODY(fo0)
        EBODY(fo1)
        // rotate pipeline
        fo0 = go2; fo1 = go3;
    }

    // K[126,126] = lane 63's E slot after diagonal 252. Plain store, no atomic.
    if (lane == 63) {
        float w = (g == 1) ? (-2.0f / 1024.0f) : (1.0f / 1024.0f);
        pws[p] = w * p1E;
    }
}

__global__ __launch_bounds__(256) void reduce_kernel(const float* __restrict__ pws,
                                                     float* __restrict__ out) {
    // Sum 3072 weighted partials (768 float4 loads), write out[0].
    float s = 0.0f;
    const float4* v = (const float4*)pws;
    for (int i = threadIdx.x; i < 768; i += 256) {
        float4 t = v[i];
        s += (t.x + t.y) + (t.z + t.w);
    }
    for (int off = 32; off > 0; off >>= 1) s += __shfl_down(s, off);
    __shared__ float ws[4];
    if ((threadIdx.x & 63) == 0) ws[threadIdx.x >> 6] = s;
    __syncthreads();
    if (threadIdx.x == 0) out[0] = (ws[0] + ws[1]) + (ws[2] + ws[3]);
}

extern "C" void kernel_launch(void* const* d_in, const int* in_sizes, int n_in,
                              void* d_out, int out_size, void* d_ws, size_t ws_size,
                              hipStream_t stream) {
    const float* x = (const float*)d_in[0];
    const float* y = (const float*)d_in[1];
    float* out = (float*)d_out;
    float* pws = (float*)d_ws;    // 3072 floats = 12 KB << ws_size
    (void)in_sizes; (void)n_in; (void)out_size; (void)ws_size;

    hipLaunchKernelGGL(sigpde_kernel, dim3(768), dim3(256), 0, stream, x, y, pws);
    hipLaunchKernelGGL(reduce_kernel, dim3(1), dim3(256), 0, stream, pws, out);
}

// Round 5
// 69.407 us; speedup vs baseline: 1.0762x; 1.0261x over previous
//
#include <hip/hip_runtime.h>

// Signature-kernel MMD, fused. R17 = R16 (71.22us verified) + PDE-loop-only
// instruction trims (model: PDE instrs cost ~7ns each, Gram ~2.8ns):
//  (1) v_fma_mix_f32 replaces cvt_f32_f16+fma in the fp16->f32 conversion
//      (src0 read as f16 via op_sel_hi, 0.25 from SGPR, -1.0 inline).
//      Bit-identical; -2 instrs/iter.
//  (2) full unroll of the 63-iter PDE loop: ds_read_u16 with immediate
//      offsets off one fixed base, no addr bump, no branches.
//  (3) __launch_bounds__(256,3) pins the VGPR cap (~168) so the unrolled
//      scheduler can't hoist loads past the 3-waves/SIMD occupancy cliff.

constexpr int S2  = 66;     // binc row stride (fp16 elems)
constexpr int PAD = 64;     // front pad (covers negative column offsets)
constexpr int BNA = 4368;   // per-pair buffer (PAD + 63*66 + rear pad, 16B-mult)

__device__ __forceinline__ float dpp_shr1(float v) {
    // result[l] = src[l-1], result[0] = 0   (wave_shr:1)
    return __builtin_bit_cast(float,
        __builtin_amdgcn_update_dpp(0, __builtin_bit_cast(int, v), 0x138, 0xF, 0xF, true));
}
__device__ __forceinline__ float dpp_shl1(float v) {
    // result[l] = src[l+1], result[63] = 0  (wave_shl:1)
    return __builtin_bit_cast(float,
        __builtin_amdgcn_update_dpp(0, __builtin_bit_cast(int, v), 0x130, 0xF, 0xF, true));
}
__device__ __forceinline__ float dot4(float4 a, float4 b) {
    return a.x * b.x + a.y * b.y + a.z * b.z + a.w * b.w;
}
// One-instruction convert-and-fold: (float)h * 0.25 - 1.0, h read as f16
// from the low half of its VGPR. Exact: f16->f32 is lossless, then fused.
__device__ __forceinline__ float cvt25m1(_Float16 h, float q25) {
    float r;
    asm("v_fma_mix_f32 %0, %1, %2, -1.0 op_sel_hi:[1,0,0]"
        : "=v"(r) : "v"(h), "s"(q25));
    return r;
}

// Two PDE substeps (antidiagonals 2k-1, 2k); ef/of are 0.25*binc-MINUS-ONE
// values (folded at f32 conversion). Per substep: dpp + 2x(add+fma).
// State: p1E,p1O (diag d-1), p2E (E diag d-2), up2 (shr1 of O diag d-2),
// oP (previous body's of). Structure verified R3/R6; folds verified R14/R16.
#define BODY(ef, of) {                                 \
    float up1 = dpp_shr1(p1O);                         \
    float cE  = (up1 + p1E) + up2 * (ef);              \
    float cO  = (p1E + p1O) + p2E * oP;                \
    float nu2 = up1, np2 = p1E;                        \
    p1E = cE; p1O = cO;                                \
    up1 = dpp_shr1(p1O);                               \
    cE  = (up1 + p1E) + nu2 * (ef);                    \
    cO  = (p1E + p1O) + np2 * (of);                    \
    up2 = up1; p2E = p1E; p1E = cE; p1O = cO;          \
    oP  = (of); }

// Body with E derived from previous body's O float via DPP (verified R7/R8).
#define EBODY(foCur) {                                 \
    float eF = dpp_shr1(foPrev);                       \
    BODY(eF, foCur)                                    \
    foPrev = (foCur); }

__global__ __launch_bounds__(256, 3) void sigpde_kernel(const float* __restrict__ x,
                                                        const float* __restrict__ y,
                                                        float* __restrict__ pws) {
    __shared__ __align__(16) _Float16 binc[4][BNA];   // 34944 B
    __shared__ float4 xs[4][64];                      //  4096 B
    __shared__ float  xxs[4][64];                     //  1024 B

    const int lane = threadIdx.x & 63;
    const int wid  = threadIdx.x >> 6;
    const int p = blockIdx.x * 4 + wid;     // 0..3071
    const int g = p >> 10;                  // 0: xx, 1: xy, 2: yy
    const int q = p & 1023;
    const int a = q >> 5, b = q & 31;
    const float* Ab = (g == 2) ? y : x;
    const float* Bb = (g == 0) ? x : y;

    _Float16* bw = &binc[wid][0];

    const float C   = -0.72134752044448170f;  // -0.5*log2(e)
    const float L2E =  1.44269504088896340f;  // log2(e) = -2*C

    float4 xa = ((const float4*)(Ab + a * 256))[lane];
    float4 yv = ((const float4*)(Bb + b * 256))[lane];
    xs[wid][lane]  = xa;
    xxs[wid][lane] = C * dot4(xa, xa);        // pre-scaled by C
    const float cyy = C * dot4(yv, yv);       // lane-constant, pre-scaled

    {   // zero this wave's buffer (pads/gaps must be finite zeros)
        uint4* z = (uint4*)bw;
        const uint4 zz = {0u, 0u, 0u, 0u};
        #pragma unroll
        for (int j = 0; j < 8; ++j) z[lane + 64 * j] = zz;  // 512 of 546
        if (lane < 34) z[512 + lane] = zz;                   // tail
    }
    // No barrier anywhere: all LDS is wave-private; same-wave ds ordering
    // is guaranteed via lgkmcnt.

    // De-phase the 3 co-resident blocks per CU (one-time, <=1280 cyc).
    {
        const int ph = blockIdx.x % 3;
        if (ph == 1)      __builtin_amdgcn_s_sleep(10);  // ~640 cyc
        else if (ph == 2) __builtin_amdgcn_s_sleep(20);  // ~1280 cyc
    }

    // Gram + double increments (column = lane), verified R6/R16:
    // gv = exp2(fma(xy, log2e, cxx+cyy)); store RAW (d - dp) fp16.
    float dp;
    {   // peeled u = 0
        float4 x0 = xs[wid][0];
        float g0 = __builtin_amdgcn_exp2f(
            __builtin_fmaf(dot4(x0, yv), L2E, xxs[wid][0] + cyy));
        dp = dpp_shl1(g0) - g0;
    }
    #pragma unroll 3
    for (int u = 1; u < 64; ++u) {
        float4 xu = xs[wid][u];            // broadcast read
        float gv = __builtin_amdgcn_exp2f(
            __builtin_fmaf(dot4(xu, yv), L2E, xxs[wid][u] + cyy));
        float d = dpp_shl1(gv) - gv;
        bw[PAD + (u - 1) * S2 + lane] = (_Float16)(d - dp);
        dp = d;
    }

    // Goursat PDE: lane owns rows iE=2l, iO=2l+1; body k = diagonals 2k-1,2k.
    // Single O-stream: body k loads oA[k-1] = binc[l][k-1-l]; the E factor is
    // eF(k) = shr1(oF(k-1)) (lane l-1's O value of the previous body).
    const int rO = (lane <= 62) ? lane : 62;
    const _Float16* oA = bw + PAD + rO * S2 - lane;
    const float q25 = 0.25f;                // lives in an SGPR for v_fma_mix

    float p1E = (lane == 0) ? 1.0f : 0.0f;  // diag 0 seed: K[0,0]=1
    float p1O = 0.0f, p2E = 0.0f, up2 = 0.0f;
    float oP = -1.0f;                       // (0*0.25 - 1): fold convention
    float foPrev = -1.0f;                   // oF(0): out-of-window 0 -> -1

    // warmup: bodies 1,2 converted; bodies 3,4 in flight (R14 structure)
    _Float16 ho2 = oA[2], ho3 = oA[3];
    float fo0 = cvt25m1(oA[0], q25);
    float fo1 = cvt25m1(oA[1], q25);

    #pragma unroll
    for (int k = 1; k <= 125; k += 2) {
        // convert bodies k+2, k+3 (loaded last iteration): one v_fma_mix each
        float go2 = cvt25m1(ho2, q25);
        float go3 = cvt25m1(ho3, q25);
        // prefetch bodies k+4, k+5 (immediate-offset ds_read after unroll)
        ho2 = oA[k + 3]; ho3 = oA[k + 4];
        // compute bodies k, k+1
        EBODY(fo0)
        EBODY(fo1)
        // rotate pipeline
        fo0 = go2; fo1 = go3;
    }

    // K[126,126] = lane 63's E slot after diagonal 252. Plain store, no atomic.
    if (lane == 63) {
        float w = (g == 1) ? (-2.0f / 1024.0f) : (1.0f / 1024.0f);
        pws[p] = w * p1E;
    }
}

__global__ __launch_bounds__(256) void reduce_kernel(const float* __restrict__ pws,
                                                     float* __restrict__ out) {
    // Sum 3072 weighted partials (768 float4 loads), write out[0].
    float s = 0.0f;
    const float4* v = (const float4*)pws;
    for (int i = threadIdx.x; i < 768; i += 256) {
        float4 t = v[i];
        s += (t.x + t.y) + (t.z + t.w);
    }
    for (int off = 32; off > 0; off >>= 1) s += __shfl_down(s, off);
    __shared__ float ws[4];
    if ((threadIdx.x & 63) == 0) ws[threadIdx.x >> 6] = s;
    __syncthreads();
    if (threadIdx.x == 0) out[0] = (ws[0] + ws[1]) + (ws[2] + ws[3]);
}

extern "C" void kernel_launch(void* const* d_in, const int* in_sizes, int n_in,
                              void* d_out, int out_size, void* d_ws, size_t ws_size,
                              hipStream_t stream) {
    const float* x = (const float*)d_in[0];
    const float* y = (const float*)d_in[1];
    float* out = (float*)d_out;
    float* pws = (float*)d_ws;    // 3072 floats = 12 KB << ws_size
    (void)in_sizes; (void)n_in; (void)out_size; (void)ws_size;

    hipLaunchKernelGGL(sigpde_kernel, dim3(768), dim3(256), 0, stream, x, y, pws);
    hipLaunchKernelGGL(reduce_kernel, dim3(1), dim3(256), 0, stream, pws, out);
}

// Round 6
// 68.150 us; speedup vs baseline: 1.0961x; 1.0184x over previous
//
#include <hip/hip_runtime.h>

// Signature-kernel MMD, fused. R18 = R17 (69.41us verified) + PDE/Gram
// data-movement trims under the confirmed issue-bound model (~7ns/instr PDE,
// ~2.8ns/instr Gram):
//  (1) Row-contiguous O-stream: lane l's PDE factor stream is row l of binc.
//      Stride S2=73 ((S2-1)%8==0) makes every lane's stream base 16B-aligned
//      -> 126 ds_read_u16 become 16 ds_read_b128 (8 fp16/read).
//  (2) Additive bank-skew A(row)=16*((row>>3)&7) folded into row starts:
//      the stride-1168B conflict group (lanes 8 apart) spreads over 8x4
//      banks -> conflict-free b128. A() is compile-time on the write side,
//      folded once into the read base. Zero runtime cost.
//  (3) Inline v_fma_mix conversions with op_sel lo/hi off chunk registers
//      (drops the 2-deep fp16 rotation pipeline).
//  (4) Full unroll of the Gram u-loop (imm-offset LDS ops, no addr bumps).
// Safety: out-of-window factor reads (col<0 / col>62) hit neighbor-row data
// (finite) instead of pad zeros; they are always multiplied by exactly-zero
// wavefront state (up2/p2E reference col-1 cells), so only FINITENESS is
// required. All consumed factors (col 0..62) map exactly:
// read byte 128+144l+A(l)+2j == write byte of (row l, col j-l).

constexpr int PAD2 = 128;   // front pad bytes
constexpr int BNA  = 4800;  // per-pair buffer in fp16 elems (9600 B, 16B-mult)

// write byte offset of (row r, col c=lane): 128 + 146r + A(r) + 2c
#define WOFF(r) (PAD2 + 146 * (r) + ((((r) >> 3) & 7) << 4))

__device__ __forceinline__ float dpp_shr1(float v) {
    // result[l] = src[l-1], result[0] = 0   (wave_shr:1)
    return __builtin_bit_cast(float,
        __builtin_amdgcn_update_dpp(0, __builtin_bit_cast(int, v), 0x138, 0xF, 0xF, true));
}
__device__ __forceinline__ float dpp_shl1(float v) {
    // result[l] = src[l+1], result[63] = 0  (wave_shl:1)
    return __builtin_bit_cast(float,
        __builtin_amdgcn_update_dpp(0, __builtin_bit_cast(int, v), 0x130, 0xF, 0xF, true));
}
__device__ __forceinline__ float dot4(float4 a, float4 b) {
    return a.x * b.x + a.y * b.y + a.z * b.z + a.w * b.w;
}
// Convert-and-fold from packed u32: (float)f16 * 0.25 - 1.0. Exact.
__device__ __forceinline__ float cvtLO(unsigned u, float q25) {
    float r;
    asm("v_fma_mix_f32 %0, %1, %2, -1.0 op_sel_hi:[1,0,0]"
        : "=v"(r) : "v"(u), "s"(q25));
    return r;
}
__device__ __forceinline__ float cvtHI(unsigned u, float q25) {
    float r;
    asm("v_fma_mix_f32 %0, %1, %2, -1.0 op_sel:[1,0,0] op_sel_hi:[1,0,0]"
        : "=v"(r) : "v"(u), "s"(q25));
    return r;
}

// Two PDE substeps (antidiagonals 2k-1, 2k); ef/of are 0.25*binc-MINUS-ONE
// values (folded at f32 conversion). Per substep: dpp + 2x(add+fma).
// Structure verified R3/R6; folds verified R14/R16/R17.
#define BODY(ef, of) {                                 \
    float up1 = dpp_shr1(p1O);                         \
    float cE  = (up1 + p1E) + up2 * (ef);              \
    float cO  = (p1E + p1O) + p2E * oP;                \
    float nu2 = up1, np2 = p1E;                        \
    p1E = cE; p1O = cO;                                \
    up1 = dpp_shr1(p1O);                               \
    cE  = (up1 + p1E) + nu2 * (ef);                    \
    cO  = (p1E + p1O) + np2 * (of);                    \
    up2 = up1; p2E = p1E; p1E = cE; p1O = cO;          \
    oP  = (of); }

// Body with E derived from previous body's O float via DPP (verified R7/R8).
#define EBODY(foCur) {                                 \
    float foC = (foCur);                               \
    float eF  = dpp_shr1(foPrev);                      \
    BODY(eF, foC)                                      \
    foPrev = foC; }

// 8 bodies off one uint4 chunk (slots x.lo, x.hi, y.lo, y.hi, z.lo, ...).
#define EBODY8(ch) {                                   \
    EBODY(cvtLO(ch.x, q25)) EBODY(cvtHI(ch.x, q25))    \
    EBODY(cvtLO(ch.y, q25)) EBODY(cvtHI(ch.y, q25))    \
    EBODY(cvtLO(ch.z, q25)) EBODY(cvtHI(ch.z, q25))    \
    EBODY(cvtLO(ch.w, q25)) EBODY(cvtHI(ch.w, q25)) }

__global__ __launch_bounds__(256, 3) void sigpde_kernel(const float* __restrict__ x,
                                                        const float* __restrict__ y,
                                                        float* __restrict__ pws) {
    __shared__ __align__(16) _Float16 binc[4][BNA];   // 38400 B
    __shared__ float4 xs[4][64];                      //  4096 B
    __shared__ float  xxs[4][64];                     //  1024 B

    const int lane = threadIdx.x & 63;
    const int wid  = threadIdx.x >> 6;
    const int p = blockIdx.x * 4 + wid;     // 0..3071
    const int g = p >> 10;                  // 0: xx, 1: xy, 2: yy
    const int q = p & 1023;
    const int a = q >> 5, b = q & 31;
    const float* Ab = (g == 2) ? y : x;
    const float* Bb = (g == 0) ? x : y;

    _Float16* bw = &binc[wid][0];

    const float C   = -0.72134752044448170f;  // -0.5*log2(e)
    const float L2E =  1.44269504088896340f;  // log2(e) = -2*C

    float4 xa = ((const float4*)(Ab + a * 256))[lane];
    float4 yv = ((const float4*)(Bb + b * 256))[lane];
    xs[wid][lane]  = xa;
    xxs[wid][lane] = C * dot4(xa, xa);        // pre-scaled by C
    const float cyy = C * dot4(yv, yv);       // lane-constant, pre-scaled

    {   // zero this wave's buffer (pads/gaps/overreads must be finite)
        uint4* z = (uint4*)bw;
        const uint4 zz = {0u, 0u, 0u, 0u};
        #pragma unroll
        for (int j = 0; j < 9; ++j) z[lane + 64 * j] = zz;  // 576 of 600
        if (lane < 24) z[576 + lane] = zz;                   // tail
    }
    // No barrier anywhere: all LDS is wave-private; same-wave ds ordering
    // is guaranteed via lgkmcnt.

    // De-phase the 3 co-resident blocks per CU (one-time, <=1280 cyc).
    {
        const int ph = blockIdx.x % 3;
        if (ph == 1)      __builtin_amdgcn_s_sleep(10);  // ~640 cyc
        else if (ph == 2) __builtin_amdgcn_s_sleep(20);  // ~1280 cyc
    }

    // Gram + double increments (column = lane), verified R6/R16:
    // gv = exp2(fma(xy, log2e, cxx+cyy)); store RAW (d - dp) fp16 at the
    // skewed row offset WOFF(u-1) + 2*lane (compile-time per u).
    char* bwh = (char*)bw + 2 * lane;
    float dp;
    {   // peeled u = 0
        float4 x0 = xs[wid][0];
        float g0 = __builtin_amdgcn_exp2f(
            __builtin_fmaf(dot4(x0, yv), L2E, xxs[wid][0] + cyy));
        dp = dpp_shl1(g0) - g0;
    }
    #pragma unroll
    for (int u = 1; u < 64; ++u) {
        float4 xu = xs[wid][u];            // broadcast read
        float gv = __builtin_amdgcn_exp2f(
            __builtin_fmaf(dot4(xu, yv), L2E, xxs[wid][u] + cyy));
        float d = dpp_shl1(gv) - gv;
        *(_Float16*)(bwh + WOFF(u - 1)) = (_Float16)(d - dp);
        dp = d;
    }

    // Goursat PDE: lane owns rows iE=2l, iO=2l+1; body k = diags 2k-1,2k.
    // Lane l's factor stream = row l of binc, read as b128 chunks of 8 fp16
    // at base 128 + 144*lane + A(lane) (16B-aligned, bank-skewed).
    const char* oaB = (const char*)bw + (PAD2 + 144 * lane + (((lane >> 3) & 7) << 4));
    const float q25 = 0.25f;                // SGPR for v_fma_mix

    float p1E = (lane == 0) ? 1.0f : 0.0f;  // diag 0 seed: K[0,0]=1
    float p1O = 0.0f, p2E = 0.0f, up2 = 0.0f;
    float oP = -1.0f;                       // (0*0.25 - 1): fold convention
    float foPrev = -1.0f;                   // oF(0): out-of-window 0 -> -1

    // 3 chunks in flight (load-to-use distance = 2 full chunk-iterations).
    uint4 cA = *(const uint4*)(oaB +  0);
    uint4 cB = *(const uint4*)(oaB + 16);
    uint4 cC = *(const uint4*)(oaB + 32);

    #pragma unroll
    for (int c = 0; c < 15; ++c) {
        // consume chunk c: bodies 8c+1 .. 8c+8
        EBODY8(cA)
        // rotate + prefetch chunk c+3 (chunks 0..15 cover oA[0..127])
        cA = cB; cB = cC;
        if (c <= 12) cC = *(const uint4*)(oaB + 16 * (c + 3));
    }
    // tail: bodies 121..126 from chunk 15 (slots x.lo .. z.hi)
    EBODY(cvtLO(cA.x, q25)) EBODY(cvtHI(cA.x, q25))
    EBODY(cvtLO(cA.y, q25)) EBODY(cvtHI(cA.y, q25))
    EBODY(cvtLO(cA.z, q25)) EBODY(cvtHI(cA.z, q25))

    // K[126,126] = lane 63's E slot after diagonal 252. Plain store, no atomic.
    if (lane == 63) {
        float w = (g == 1) ? (-2.0f / 1024.0f) : (1.0f / 1024.0f);
        pws[p] = w * p1E;
    }
}

__global__ __launch_bounds__(256) void reduce_kernel(const float* __restrict__ pws,
                                                     float* __restrict__ out) {
    // Sum 3072 weighted partials (768 float4 loads), write out[0].
    float s = 0.0f;
    const float4* v = (const float4*)pws;
    for (int i = threadIdx.x; i < 768; i += 256) {
        float4 t = v[i];
        s += (t.x + t.y) + (t.z + t.w);
    }
    for (int off = 32; off > 0; off >>= 1) s += __shfl_down(s, off);
    __shared__ float ws[4];
    if ((threadIdx.x & 63) == 0) ws[threadIdx.x >> 6] = s;
    __syncthreads();
    if (threadIdx.x == 0) out[0] = (ws[0] + ws[1]) + (ws[2] + ws[3]);
}

extern "C" void kernel_launch(void* const* d_in, const int* in_sizes, int n_in,
                              void* d_out, int out_size, void* d_ws, size_t ws_size,
                              hipStream_t stream) {
    const float* x = (const float*)d_in[0];
    const float* y = (const float*)d_in[1];
    float* out = (float*)d_out;
    float* pws = (float*)d_ws;    // 3072 floats = 12 KB << ws_size
    (void)in_sizes; (void)n_in; (void)out_size; (void)ws_size;

    hipLaunchKernelGGL(sigpde_kernel, dim3(768), dim3(256), 0, stream, x, y, pws);
    hipLaunchKernelGGL(reduce_kernel, dim3(1), dim3(256), 0, stream, pws, out);
}

// Round 7
// 68.141 us; speedup vs baseline: 1.0963x; 1.0001x over previous
//
#include <hip/hip_runtime.h>

// Signature-kernel MMD, fused. R19 = R18 (68.15us verified) + packed-FP32
// PDE body. CDNA's v_pk_add_f32/v_pk_fma_f32 are full-rate (1 instr / 2cyc
// wave64, 2 results): pack the independent cE/cO streams as pairs.
//   P=(p1E,p1O)  U=(up2,p2E)  F=(eF, oP-or-of)
// Substep: W.x=dpp(P.y); W.y=P.x; P=pk_fma(U,F,pk_add(W,P)); U=W  (4 instrs
// vs 5 scalar; the mov builds next substep's U pair - amortized).
// Factor pair rolls in place, zero movs: F.x=dpp(F.y) [eF, old eF dead];
// substep1 uses (eF,oP); F.y=fma_mix(chunk) [of, old oP dead]; substep2
// uses (eF,of). Per body: 12 -> 10 issue slots. Arithmetic bit-identical
// (pk ops = IEEE f32 add/fma on identical values).

constexpr int PAD2 = 128;   // front pad bytes
constexpr int BNA  = 4800;  // per-pair buffer in fp16 elems (9600 B, 16B-mult)

// write byte offset of (row r, col c=lane): 128 + 146r + A(r) + 2c
#define WOFF(r) (PAD2 + 146 * (r) + ((((r) >> 3) & 7) << 4))

typedef float f32x2 __attribute__((ext_vector_type(2)));

__device__ __forceinline__ float dpp_shr1(float v) {
    // result[l] = src[l-1], result[0] = 0   (wave_shr:1)
    return __builtin_bit_cast(float,
        __builtin_amdgcn_update_dpp(0, __builtin_bit_cast(int, v), 0x138, 0xF, 0xF, true));
}
__device__ __forceinline__ float dpp_shl1(float v) {
    // result[l] = src[l+1], result[63] = 0  (wave_shl:1)
    return __builtin_bit_cast(float,
        __builtin_amdgcn_update_dpp(0, __builtin_bit_cast(int, v), 0x130, 0xF, 0xF, true));
}
__device__ __forceinline__ float dot4(float4 a, float4 b) {
    return a.x * b.x + a.y * b.y + a.z * b.z + a.w * b.w;
}
// Convert-and-fold from packed u32: (float)f16 * 0.25 - 1.0. Exact.
__device__ __forceinline__ float cvtLO(unsigned u, float q25) {
    float r;
    asm("v_fma_mix_f32 %0, %1, %2, -1.0 op_sel_hi:[1,0,0]"
        : "=v"(r) : "v"(u), "s"(q25));
    return r;
}
__device__ __forceinline__ float cvtHI(unsigned u, float q25) {
    float r;
    asm("v_fma_mix_f32 %0, %1, %2, -1.0 op_sel:[1,0,0] op_sel_hi:[1,0,0]"
        : "=v"(r) : "v"(u), "s"(q25));
    return r;
}
// Full-rate packed FP32 (CDNA dual-FP32 feature).
__device__ __forceinline__ f32x2 pk_add(f32x2 a, f32x2 b) {
    f32x2 r;
    asm("v_pk_add_f32 %0, %1, %2" : "=v"(r) : "v"(a), "v"(b));
    return r;
}
__device__ __forceinline__ f32x2 pk_fma(f32x2 a, f32x2 b, f32x2 c) {
    f32x2 r;
    asm("v_pk_fma_f32 %0, %1, %2, %3" : "=v"(r) : "v"(a), "v"(b), "v"(c));
    return r;
}

// One PDE substep (one antidiagonal), packed. Scalar-equivalent (verified
// R3/R6 structure): cE = up1 + p1E + up2*eF; cO = p1E + p1O + p2E*oF.
#define PSUB {                                  \
    f32x2 W;                                    \
    W.x = dpp_shr1(P.y);                        \
    W.y = P.x;                                  \
    P = pk_fma(U, F, pk_add(W, P));             \
    U = W; }

// One body = diagonals 2k-1, 2k. cvtexpr supplies of(k) = 0.25*binc - 1.
#define PBODYv(cvtexpr) {                       \
    F.x = dpp_shr1(F.y);                        \
    PSUB                                        \
    F.y = (cvtexpr);                            \
    PSUB }

// 8 bodies off one uint4 chunk (slots x.lo, x.hi, y.lo, y.hi, z.lo, ...).
#define PBODY8(ch) {                                     \
    PBODYv(cvtLO(ch.x, q25)) PBODYv(cvtHI(ch.x, q25))    \
    PBODYv(cvtLO(ch.y, q25)) PBODYv(cvtHI(ch.y, q25))    \
    PBODYv(cvtLO(ch.z, q25)) PBODYv(cvtHI(ch.z, q25))    \
    PBODYv(cvtLO(ch.w, q25)) PBODYv(cvtHI(ch.w, q25)) }

__global__ __launch_bounds__(256, 3) void sigpde_kernel(const float* __restrict__ x,
                                                        const float* __restrict__ y,
                                                        float* __restrict__ pws) {
    __shared__ __align__(16) _Float16 binc[4][BNA];   // 38400 B
    __shared__ float4 xs[4][64];                      //  4096 B
    __shared__ float  xxs[4][64];                     //  1024 B

    const int lane = threadIdx.x & 63;
    const int wid  = threadIdx.x >> 6;
    const int p = blockIdx.x * 4 + wid;     // 0..3071
    const int g = p >> 10;                  // 0: xx, 1: xy, 2: yy
    const int q = p & 1023;
    const int a = q >> 5, b = q & 31;
    const float* Ab = (g == 2) ? y : x;
    const float* Bb = (g == 0) ? x : y;

    _Float16* bw = &binc[wid][0];

    const float C   = -0.72134752044448170f;  // -0.5*log2(e)
    const float L2E =  1.44269504088896340f;  // log2(e) = -2*C

    float4 xa = ((const float4*)(Ab + a * 256))[lane];
    float4 yv = ((const float4*)(Bb + b * 256))[lane];
    xs[wid][lane]  = xa;
    xxs[wid][lane] = C * dot4(xa, xa);        // pre-scaled by C
    const float cyy = C * dot4(yv, yv);       // lane-constant, pre-scaled

    {   // zero this wave's buffer (pads/gaps/overreads must be finite)
        uint4* z = (uint4*)bw;
        const uint4 zz = {0u, 0u, 0u, 0u};
        #pragma unroll
        for (int j = 0; j < 9; ++j) z[lane + 64 * j] = zz;  // 576 of 600
        if (lane < 24) z[576 + lane] = zz;                   // tail
    }
    // No barrier anywhere: all LDS is wave-private; same-wave ds ordering
    // is guaranteed via lgkmcnt.

    // De-phase the 3 co-resident blocks per CU (one-time, <=1280 cyc).
    {
        const int ph = blockIdx.x % 3;
        if (ph == 1)      __builtin_amdgcn_s_sleep(10);  // ~640 cyc
        else if (ph == 2) __builtin_amdgcn_s_sleep(20);  // ~1280 cyc
    }

    // Gram + double increments (column = lane), verified R6/R16:
    // gv = exp2(fma(xy, log2e, cxx+cyy)); store RAW (d - dp) fp16 at the
    // skewed row offset WOFF(u-1) + 2*lane (compile-time per u).
    char* bwh = (char*)bw + 2 * lane;
    float dp;
    {   // peeled u = 0
        float4 x0 = xs[wid][0];
        float g0 = __builtin_amdgcn_exp2f(
            __builtin_fmaf(dot4(x0, yv), L2E, xxs[wid][0] + cyy));
        dp = dpp_shl1(g0) - g0;
    }
    #pragma unroll
    for (int u = 1; u < 64; ++u) {
        float4 xu = xs[wid][u];            // broadcast read
        float gv = __builtin_amdgcn_exp2f(
            __builtin_fmaf(dot4(xu, yv), L2E, xxs[wid][u] + cyy));
        float d = dpp_shl1(gv) - gv;
        *(_Float16*)(bwh + WOFF(u - 1)) = (_Float16)(d - dp);
        dp = d;
    }

    // Goursat PDE: lane owns rows iE=2l, iO=2l+1; body k = diags 2k-1,2k.
    // Lane l's factor stream = row l of binc, read as b128 chunks of 8 fp16
    // at base 128 + 144*lane + A(lane) (16B-aligned, bank-skewed).
    const char* oaB = (const char*)bw + (PAD2 + 144 * lane + (((lane >> 3) & 7) << 4));
    const float q25 = 0.25f;                // SGPR for v_fma_mix

    f32x2 P = { (lane == 0) ? 1.0f : 0.0f, 0.0f };  // (p1E, p1O); K[0,0]=1
    f32x2 U = { 0.0f, 0.0f };                        // (up2, p2E)
    f32x2 F = { -1.0f, -1.0f };                      // F.y = oF(0) = -1

    // 3 chunks in flight (load-to-use distance = 2 full chunk-iterations).
    uint4 cA = *(const uint4*)(oaB +  0);
    uint4 cB = *(const uint4*)(oaB + 16);
    uint4 cC = *(const uint4*)(oaB + 32);

    #pragma unroll
    for (int c = 0; c < 15; ++c) {
        // consume chunk c: bodies 8c+1 .. 8c+8
        PBODY8(cA)
        // rotate + prefetch chunk c+3 (chunks 0..15 cover oA[0..127])
        cA = cB; cB = cC;
        if (c <= 12) cC = *(const uint4*)(oaB + 16 * (c + 3));
    }
    // tail: bodies 121..126 from chunk 15 (slots x.lo .. z.hi)
    PBODYv(cvtLO(cA.x, q25)) PBODYv(cvtHI(cA.x, q25))
    PBODYv(cvtLO(cA.y, q25)) PBODYv(cvtHI(cA.y, q25))
    PBODYv(cvtLO(cA.z, q25)) PBODYv(cvtHI(cA.z, q25))

    // K[126,126] = lane 63's E slot after diagonal 252. Plain store, no atomic.
    if (lane == 63) {
        float w = (g == 1) ? (-2.0f / 1024.0f) : (1.0f / 1024.0f);
        pws[p] = w * P.x;
    }
}

__global__ __launch_bounds__(256) void reduce_kernel(const float* __restrict__ pws,
                                                     float* __restrict__ out) {
    // Sum 3072 weighted partials (768 float4 loads), write out[0].
    float s = 0.0f;
    const float4* v = (const float4*)pws;
    for (int i = threadIdx.x; i < 768; i += 256) {
        float4 t = v[i];
        s += (t.x + t.y) + (t.z + t.w);
    }
    for (int off = 32; off > 0; off >>= 1) s += __shfl_down(s, off);
    __shared__ float ws[4];
    if ((threadIdx.x & 63) == 0) ws[threadIdx.x >> 6] = s;
    __syncthreads();
    if (threadIdx.x == 0) out[0] = (ws[0] + ws[1]) + (ws[2] + ws[3]);
}

extern "C" void kernel_launch(void* const* d_in, const int* in_sizes, int n_in,
                              void* d_out, int out_size, void* d_ws, size_t ws_size,
                              hipStream_t stream) {
    const float* x = (const float*)d_in[0];
    const float* y = (const float*)d_in[1];
    float* out = (float*)d_out;
    float* pws = (float*)d_ws;    // 3072 floats = 12 KB << ws_size
    (void)in_sizes; (void)n_in; (void)out_size; (void)ws_size;

    hipLaunchKernelGGL(sigpde_kernel, dim3(768), dim3(256), 0, stream, x, y, pws);
    hipLaunchKernelGGL(reduce_kernel, dim3(1), dim3(256), 0, stream, pws, out);
}